// Round 8
// baseline (311.292 us; speedup 1.0000x reference)
//
#include <hip/hip_runtime.h>

#define CH 128          // channels
#define CHUNK 8192      // edges per sort chunk
#define BSH 9           // 512 nodes per bucket
#define BNODES 512
#define MAXB 256        // max buckets/chunks supported
#define NT 512          // mega-kernel threads per block

// ---- device-scope grid barrier (generation-based) --------------------------
__device__ __forceinline__ void gsync(int* bar, int nb, int it) {
    __syncthreads();
    if (threadIdx.x == 0) {
        __threadfence();   // make this block's prior writes device-visible
        if (__hip_atomic_fetch_add(&bar[0], 1, __ATOMIC_ACQ_REL,
                                   __HIP_MEMORY_SCOPE_AGENT) == nb - 1) {
            __hip_atomic_store(&bar[0], 0, __ATOMIC_RELAXED, __HIP_MEMORY_SCOPE_AGENT);
            __hip_atomic_fetch_add(&bar[1], 1, __ATOMIC_RELEASE, __HIP_MEMORY_SCOPE_AGENT);
        } else {
            while (__hip_atomic_load(&bar[1], __ATOMIC_ACQUIRE,
                                     __HIP_MEMORY_SCOPE_AGENT) < it)
                __builtin_amdgcn_s_sleep(8);
        }
        __threadfence();   // acquire side: invalidate stale cached data
    }
    __syncthreads();
}

// ---- K0: u[r] = W1[r,:].W2 (r<128) ; u[128] = beta = b1.W2 ; init barrier --
__global__ __launch_bounds__(256) void k_uw(const float* __restrict__ W1,
                                            const float* __restrict__ b1,
                                            const float* __restrict__ W2,
                                            float* __restrict__ u,
                                            int* __restrict__ bar) {
    if (blockIdx.x == 0 && threadIdx.x == 0) { bar[0] = 0; bar[1] = 0; }
    int wid  = blockIdx.x * 4 + (threadIdx.x >> 6);
    if (wid > CH) return;
    int lane = threadIdx.x & 63;
    const float* rowp = (wid < CH) ? (W1 + (size_t)wid * CH) : b1;
    float2 xv = *(const float2*)(rowp + lane * 2);
    float2 vv = *(const float2*)(W2 + lane * 2);
    float acc = xv.x * vv.x + xv.y * vv.y;
#pragma unroll
    for (int m = 32; m; m >>= 1) acc += __shfl_xor(acc, m);
    if (lane == 0) u[wid] = acc;
}

// ---- K1: t[i] = x[i,:].u — half-wave per row, 4-way unrolled for MLP -------
__global__ __launch_bounds__(256) void k_gemv(const float* __restrict__ X,
                                              const float* __restrict__ u,
                                              float* __restrict__ t, int n) {
    int hw = blockIdx.x * 8 + (threadIdx.x >> 5);   // half-wave id
    int l  = threadIdx.x & 31;
    float4 uv = *(const float4*)(u + l * 4);
    const int stride = gridDim.x * 8;
    for (int base = hw; base < n; base += stride * 4) {
        int r0 = base, r1 = base + stride, r2 = base + 2 * stride, r3 = base + 3 * stride;
        float a0 = 0.f, a1 = 0.f, a2 = 0.f, a3 = 0.f;
        if (r0 < n) { float4 x = *(const float4*)(X + (size_t)r0 * CH + l * 4);
                      a0 = x.x * uv.x + x.y * uv.y + x.z * uv.z + x.w * uv.w; }
        if (r1 < n) { float4 x = *(const float4*)(X + (size_t)r1 * CH + l * 4);
                      a1 = x.x * uv.x + x.y * uv.y + x.z * uv.z + x.w * uv.w; }
        if (r2 < n) { float4 x = *(const float4*)(X + (size_t)r2 * CH + l * 4);
                      a2 = x.x * uv.x + x.y * uv.y + x.z * uv.z + x.w * uv.w; }
        if (r3 < n) { float4 x = *(const float4*)(X + (size_t)r3 * CH + l * 4);
                      a3 = x.x * uv.x + x.y * uv.y + x.z * uv.z + x.w * uv.w; }
#pragma unroll
        for (int m = 16; m; m >>= 1) {
            a0 += __shfl_xor(a0, m); a1 += __shfl_xor(a1, m);
            a2 += __shfl_xor(a2, m); a3 += __shfl_xor(a3, m);
        }
        if (l == 0) {
            if (r0 < n) t[r0] = a0;
            if (r1 < n) t[r1] = a1;
            if (r2 < n) t[r2] = a2;
            if (r3 < n) t[r3] = a3;
        }
    }
}

// ---- K2: persistent mega-kernel: hist -> permute -> deg -> s1 -> out -------
__global__ __launch_bounds__(NT) void k_mega(const int* __restrict__ row,
                                             const int* __restrict__ col,
                                             const float* __restrict__ w,
                                             const float* __restrict__ t,
                                             const float* __restrict__ u,
                                             const float* __restrict__ b2,
                                             int2* __restrict__ ep,
                                             int* __restrict__ Ht,
                                             int* __restrict__ bstart,
                                             int* __restrict__ bar,
                                             float* __restrict__ dinv,
                                             float* __restrict__ p,
                                             float* __restrict__ q,
                                             float* __restrict__ out,
                                             int n, int e_cnt, int nbuck, int nchunk) {
    __shared__ int smem[3 * MAXB + 4];           // unioned across phases
    int*   h    = smem;                          // hist: nbuck
    int*   runS = smem;                          // permute: nbuck
    int*   curS = smem + MAXB;                   // permute: nbuck (cursors)
    int*   bs   = smem + 2 * MAXB;               // permute: nbuck+1
    float* acc  = (float*)smem;                  // agg: BNODES floats (512)

    const int b = blockIdx.x, tid = threadIdx.x;
    const int nb = gridDim.x;

    // ---- Phase A: histogram of chunk b ----
    if (b < nchunk) {
        if (tid < nbuck) h[tid] = 0;
        __syncthreads();
        int e0 = b * CHUNK, e1 = min(e0 + CHUNK, e_cnt);
        for (int e = e0 + tid; e < e1; e += NT)
            atomicAdd(&h[col[e] >> BSH], 1);
        __syncthreads();
        if (tid < nbuck) Ht[(size_t)b * nbuck + tid] = h[tid];
    }
    gsync(bar, nb, 1);

    // ---- Phase B: permute (each block derives its own prefix from Ht) ----
    if (b < nchunk) {
        if (tid < nbuck) {
            int run = 0, pre = 0;
            for (int c = 0; c < nchunk; ++c) {
                int v = Ht[(size_t)c * nbuck + tid];
                run += v;
                if (c < b) pre += v;
            }
            runS[tid] = run;
            curS[tid] = pre;
        }
        __syncthreads();
        if (tid < 64) {   // single-wave exclusive scan of runS -> bs
            int vals[4]; int sum = 0;
#pragma unroll
            for (int k = 0; k < 4; ++k) {
                int idx = tid * 4 + k;
                vals[k] = (idx < nbuck) ? runS[idx] : 0;
                sum += vals[k];
            }
            int incl = sum;
#pragma unroll
            for (int d = 1; d < 64; d <<= 1) {
                int up = __shfl_up(incl, d);
                if (tid >= d) incl += up;
            }
            int run2 = incl - sum;
#pragma unroll
            for (int k = 0; k < 4; ++k) {
                int idx = tid * 4 + k;
                if (idx < nbuck) bs[idx] = run2;
                run2 += vals[k];
            }
            if (tid == 63) bs[nbuck] = run2;
        }
        __syncthreads();
        if (tid < nbuck) curS[tid] += bs[tid];
        __syncthreads();
        int e0 = b * CHUNK, e1 = min(e0 + CHUNK, e_cnt);
        for (int e = e0 + tid; e < e1; e += NT) {
            int r = row[e], c = col[e];
            float wv = w[e];
            int pos = atomicAdd(&curS[c >> BSH], 1);
            ep[pos] = make_int2(r | ((c & (BNODES - 1)) << 17), __float_as_int(wv));
        }
        if (b == 0 && tid <= nbuck) bstart[tid] = bs[tid];
    }
    gsync(bar, nb, 2);

    // ---- Phase C: degree agg -> dinv, p = dinv*t ----
    if (b < nbuck) {
        acc[tid] = 0.f;
        __syncthreads();
        int j0 = bstart[b], j1 = bstart[b + 1];
        for (int j = j0 + tid; j < j1; j += NT) {
            int2 kv = ep[j];
            atomicAdd(&acc[kv.x >> 17], __int_as_float(kv.y));
        }
        __syncthreads();
        int node = (b << BSH) + tid;
        if (node < n) {
            float di = rsqrtf(1.0f + acc[tid]);   // +1 = self-loop
            dinv[node] = di;
            p[node] = di * t[node];
        }
    }
    gsync(bar, nb, 3);

    // ---- Phase D: s1 agg -> q = dinv*(s1+beta) ----
    if (b < nbuck) {
        acc[tid] = 0.f;
        __syncthreads();
        float beta = u[CH];
        int j0 = bstart[b], j1 = bstart[b + 1];
        for (int j = j0 + tid; j < j1; j += NT) {
            int2 kv = ep[j];
            atomicAdd(&acc[kv.x >> 17], __int_as_float(kv.y) * p[kv.x & 0x1FFFF]);
        }
        __syncthreads();
        int node = (b << BSH) + tid;
        if (node < n) {
            float di = dinv[node];
            float s1 = di * (p[node] + acc[tid]);   // p = self-loop term dinv*t
            q[node] = di * (s1 + beta);
        }
    }
    gsync(bar, nb, 4);

    // ---- Phase E: out agg: out = b2 + dinv*(q + sum w*q[src]) ----
    if (b < nbuck) {
        acc[tid] = 0.f;
        __syncthreads();
        int j0 = bstart[b], j1 = bstart[b + 1];
        for (int j = j0 + tid; j < j1; j += NT) {
            int2 kv = ep[j];
            atomicAdd(&acc[kv.x >> 17], __int_as_float(kv.y) * q[kv.x & 0x1FFFF]);
        }
        __syncthreads();
        int node = (b << BSH) + tid;
        if (node < n)
            out[node] = b2[0] + dinv[node] * (q[node] + acc[tid]);
    }
}

extern "C" void kernel_launch(void* const* d_in, const int* in_sizes, int n_in,
                              void* d_out, int out_size, void* d_ws, size_t ws_size,
                              hipStream_t stream) {
    const float* x   = (const float*)d_in[0];
    const int*   ei  = (const int*)d_in[1];
    const float* w   = (const float*)d_in[2];
    const float* W1  = (const float*)d_in[3];
    const float* b1  = (const float*)d_in[4];
    const float* W2  = (const float*)d_in[5];
    const float* b2  = (const float*)d_in[6];
    float* out = (float*)d_out;

    const int n     = in_sizes[0] / CH;    // 100000
    const int e_cnt = in_sizes[2];         // 1600000
    const int* row = ei;
    const int* col = ei + e_cnt;

    const int nbuck  = (n + BNODES - 1) >> BSH;         // 196
    const int nchunk = (e_cnt + CHUNK - 1) / CHUNK;     // 196
    const int nblk   = (nbuck > nchunk) ? nbuck : nchunk;  // 196 (<=256 CUs: co-resident)

    // ---- workspace layout (ep first for 8B alignment) ----
    int2*  ep     = (int2*)d_ws;                        // e_cnt int2
    float* u      = (float*)(ep + e_cnt);               // 132
    float* t      = u + 132;                            // n
    float* dinv   = t + n;                              // n
    float* p      = dinv + n;                           // n
    float* q      = p + n;                              // n
    int*   bstart = (int*)(q + n);                      // nbuck+1
    int*   bar    = bstart + nbuck + 1;                 // 2
    int*   Ht     = bar + 2;                            // nchunk*nbuck

    k_uw<<<(CH + 1 + 3) / 4, 256, 0, stream>>>(W1, b1, W2, u, bar);
    k_gemv<<<1024, 256, 0, stream>>>(x, u, t, n);
    k_mega<<<nblk, NT, 0, stream>>>(row, col, w, t, u, b2,
                                    ep, Ht, bstart, bar,
                                    dinv, p, q, out,
                                    n, e_cnt, nbuck, nchunk);
}

// Round 9
// 181.281 us; speedup vs baseline: 1.7172x; 1.7172x over previous
//
#include <hip/hip_runtime.h>

#define CH 128          // channels
#define CHUNK 8192      // edges per sort chunk
#define BSH 8           // 256 nodes per bucket
#define BNODES 256
#define MAXB 512        // max buckets/chunks supported (n <= 131072)
#define PNT 512         // permute threads
#define AGG_NT 1024     // aggregation threads
#define GEMV_BLOCKS 1024

// ---- A: blocks [0,nchunk) = per-chunk histogram; block nchunk = u=W1@W2 ----
__global__ __launch_bounds__(256) void k_uw_hist(const float* __restrict__ W1,
                                                 const float* __restrict__ b1,
                                                 const float* __restrict__ W2,
                                                 float* __restrict__ u,
                                                 const int* __restrict__ col,
                                                 int* __restrict__ Ht,
                                                 int nbuck, int nchunk, int e_cnt) {
    __shared__ int h[MAXB];
    int b = blockIdx.x, tid = threadIdx.x;
    if (b == nchunk) {             // ---- uw: 129 rows, 4 waves round-robin
        int wv = tid >> 6, lane = tid & 63;
        float2 vv = *(const float2*)(W2 + lane * 2);
        for (int r = wv; r <= CH; r += 4) {
            const float* rowp = (r < CH) ? (W1 + (size_t)r * CH) : b1;
            float2 xv = *(const float2*)(rowp + lane * 2);
            float acc = xv.x * vv.x + xv.y * vv.y;
#pragma unroll
            for (int m = 32; m; m >>= 1) acc += __shfl_xor(acc, m);
            if (lane == 0) u[r] = acc;
        }
        return;
    }
    for (int k = tid; k < nbuck; k += 256) h[k] = 0;
    __syncthreads();
    int e0 = b * CHUNK, e1 = min(e0 + CHUNK, e_cnt);
    for (int e = e0 + tid; e < e1; e += 256)
        atomicAdd(&h[col[e] >> BSH], 1);
    __syncthreads();
    for (int k = tid; k < nbuck; k += 256) Ht[(size_t)b * nbuck + k] = h[k];
}

// ---- B: blocks [0,nbCols) = column scan Ht->Hs ; rest = gemv t = x.u -------
__global__ __launch_bounds__(256) void k_gemv_colscan(const float* __restrict__ X,
                                                      const float* __restrict__ u,
                                                      float* __restrict__ t,
                                                      const int* __restrict__ Ht,
                                                      int* __restrict__ Hs,
                                                      int* __restrict__ coltot,
                                                      int n, int nchunk, int nbuck,
                                                      int nbCols) {
    int b = blockIdx.x, tid = threadIdx.x;
    if (b < nbCols) {              // ---- colscan: wave per column
        int j = b * 4 + (tid >> 6);
        if (j >= nbuck) return;
        int lane = tid & 63;
        int run = 0;
        for (int base = 0; base < nchunk; base += 64) {
            int idx = base + lane;
            int v = (idx < nchunk) ? Ht[(size_t)idx * nbuck + j] : 0;
            int incl = v;
#pragma unroll
            for (int d = 1; d < 64; d <<= 1) {
                int up = __shfl_up(incl, d);
                if (lane >= d) incl += up;
            }
            if (idx < nchunk) Hs[(size_t)idx * nbuck + j] = run + incl - v;
            run += __shfl(incl, 63);
        }
        if (lane == 0) coltot[j] = run;
        return;
    }
    // ---- gemv: half-wave per row, 4-way unrolled
    int gb = b - nbCols;
    int hw = gb * 8 + (tid >> 5);
    int l  = tid & 31;
    float4 uv = *(const float4*)(u + l * 4);
    const int stride = GEMV_BLOCKS * 8;
    for (int base = hw; base < n; base += stride * 4) {
        int r0 = base, r1 = base + stride, r2 = base + 2 * stride, r3 = base + 3 * stride;
        float a0 = 0.f, a1 = 0.f, a2 = 0.f, a3 = 0.f;
        if (r0 < n) { float4 x = *(const float4*)(X + (size_t)r0 * CH + l * 4);
                      a0 = x.x * uv.x + x.y * uv.y + x.z * uv.z + x.w * uv.w; }
        if (r1 < n) { float4 x = *(const float4*)(X + (size_t)r1 * CH + l * 4);
                      a1 = x.x * uv.x + x.y * uv.y + x.z * uv.z + x.w * uv.w; }
        if (r2 < n) { float4 x = *(const float4*)(X + (size_t)r2 * CH + l * 4);
                      a2 = x.x * uv.x + x.y * uv.y + x.z * uv.z + x.w * uv.w; }
        if (r3 < n) { float4 x = *(const float4*)(X + (size_t)r3 * CH + l * 4);
                      a3 = x.x * uv.x + x.y * uv.y + x.z * uv.z + x.w * uv.w; }
#pragma unroll
        for (int m = 16; m; m >>= 1) {
            a0 += __shfl_xor(a0, m); a1 += __shfl_xor(a1, m);
            a2 += __shfl_xor(a2, m); a3 += __shfl_xor(a3, m);
        }
        if (l == 0) {
            if (r0 < n) t[r0] = a0;
            if (r1 < n) t[r1] = a1;
            if (r2 < n) t[r2] = a2;
            if (r3 < n) t[r3] = a3;
        }
    }
}

// ---- C: permute edges -> bucket-sorted int2; block 0 publishes bstart ------
__global__ __launch_bounds__(PNT) void k_permute(const int* __restrict__ row,
                                                 const int* __restrict__ col,
                                                 const float* __restrict__ w,
                                                 const int* __restrict__ Hs,
                                                 const int* __restrict__ coltot,
                                                 int* __restrict__ bstart,
                                                 int2* __restrict__ ep,
                                                 int nbuck, int e_cnt) {
    __shared__ int bs[MAXB + 1];
    __shared__ int cur[MAXB];
    int b = blockIdx.x, tid = threadIdx.x;
    if (tid < 64) {   // single-wave exclusive scan of coltot -> bs
        int run = 0;
        for (int base = 0; base < nbuck; base += 64) {
            int idx = base + tid;
            int v = (idx < nbuck) ? coltot[idx] : 0;
            int incl = v;
#pragma unroll
            for (int d = 1; d < 64; d <<= 1) {
                int up = __shfl_up(incl, d);
                if (tid >= d) incl += up;
            }
            if (idx < nbuck) bs[idx] = run + incl - v;
            run += __shfl(incl, 63);
        }
        if (tid == 0) bs[nbuck] = run;
    }
    __syncthreads();
    for (int k = tid; k < nbuck; k += PNT)
        cur[k] = bs[k] + Hs[(size_t)b * nbuck + k];
    __syncthreads();
    int e0 = b * CHUNK, e1 = min(e0 + CHUNK, e_cnt);
    for (int e = e0 + tid; e < e1; e += PNT) {
        int r = row[e], c = col[e];
        float wv = w[e];
        int pos = atomicAdd(&cur[c >> BSH], 1);
        ep[pos] = make_int2(r | ((c & (BNODES - 1)) << 17), __float_as_int(wv));
    }
    if (b == 0)
        for (int k = tid; k <= nbuck; k += PNT) bstart[k] = bs[k];
}

// ---- D: deg agg (block owns bucket) -> dinv, p = dinv*t --------------------
__global__ __launch_bounds__(AGG_NT) void k_adeg(const int2* __restrict__ ep,
                                                 const int* __restrict__ bstart,
                                                 const float* __restrict__ t,
                                                 float* __restrict__ dinv,
                                                 float* __restrict__ p, int n) {
    __shared__ float acc[BNODES];
    int b = blockIdx.x, tid = threadIdx.x;
    if (tid < BNODES) acc[tid] = 0.f;
    __syncthreads();
    int j1 = bstart[b + 1];
    for (int j = bstart[b] + tid; j < j1; j += AGG_NT) {
        int2 kv = ep[j];
        atomicAdd(&acc[kv.x >> 17], __int_as_float(kv.y));
    }
    __syncthreads();
    int node = (b << BSH) + tid;
    if (tid < BNODES && node < n) {
        float di = rsqrtf(1.0f + acc[tid]);   // +1 = self-loop
        dinv[node] = di;
        p[node] = di * t[node];
    }
}

// ---- E: s1 agg -> q = dinv*(s1+beta) ---------------------------------------
__global__ __launch_bounds__(AGG_NT) void k_as1(const int2* __restrict__ ep,
                                                const int* __restrict__ bstart,
                                                const float* __restrict__ p,
                                                const float* __restrict__ dinv,
                                                const float* __restrict__ u,
                                                float* __restrict__ q, int n) {
    __shared__ float acc[BNODES];
    int b = blockIdx.x, tid = threadIdx.x;
    if (tid < BNODES) acc[tid] = 0.f;
    __syncthreads();
    int j1 = bstart[b + 1];
    for (int j = bstart[b] + tid; j < j1; j += AGG_NT) {
        int2 kv = ep[j];
        atomicAdd(&acc[kv.x >> 17], __int_as_float(kv.y) * p[kv.x & 0x1FFFF]);
    }
    __syncthreads();
    int node = (b << BSH) + tid;
    if (tid < BNODES && node < n) {
        float di = dinv[node];
        float s1 = di * (p[node] + acc[tid]);   // p = self-loop term dinv*t
        q[node] = di * (s1 + u[CH]);
    }
}

// ---- F: out agg: out = b2 + dinv*(q + sum w*q[src]) ------------------------
__global__ __launch_bounds__(AGG_NT) void k_aout(const int2* __restrict__ ep,
                                                 const int* __restrict__ bstart,
                                                 const float* __restrict__ q,
                                                 const float* __restrict__ dinv,
                                                 const float* __restrict__ b2,
                                                 float* __restrict__ out, int n) {
    __shared__ float acc[BNODES];
    int b = blockIdx.x, tid = threadIdx.x;
    if (tid < BNODES) acc[tid] = 0.f;
    __syncthreads();
    int j1 = bstart[b + 1];
    for (int j = bstart[b] + tid; j < j1; j += AGG_NT) {
        int2 kv = ep[j];
        atomicAdd(&acc[kv.x >> 17], __int_as_float(kv.y) * q[kv.x & 0x1FFFF]);
    }
    __syncthreads();
    int node = (b << BSH) + tid;
    if (tid < BNODES && node < n)
        out[node] = b2[0] + dinv[node] * (q[node] + acc[tid]);
}

extern "C" void kernel_launch(void* const* d_in, const int* in_sizes, int n_in,
                              void* d_out, int out_size, void* d_ws, size_t ws_size,
                              hipStream_t stream) {
    const float* x   = (const float*)d_in[0];
    const int*   ei  = (const int*)d_in[1];
    const float* w   = (const float*)d_in[2];
    const float* W1  = (const float*)d_in[3];
    const float* b1  = (const float*)d_in[4];
    const float* W2  = (const float*)d_in[5];
    const float* b2  = (const float*)d_in[6];
    float* out = (float*)d_out;

    const int n     = in_sizes[0] / CH;    // 100000
    const int e_cnt = in_sizes[2];         // 1600000
    const int* row = ei;
    const int* col = ei + e_cnt;

    const int nbuck  = (n + BNODES - 1) >> BSH;         // 391
    const int nchunk = (e_cnt + CHUNK - 1) / CHUNK;     // 196
    const int nbCols = (nbuck + 3) / 4;                 // 98

    // ---- workspace layout (ep first for 8B alignment) ----
    int2*  ep     = (int2*)d_ws;                        // e_cnt int2
    float* u      = (float*)(ep + e_cnt);               // 132
    float* t      = u + 132;                            // n
    float* dinv   = t + n;                              // n
    float* p      = dinv + n;                           // n
    float* q      = p + n;                              // n
    int*   coltot = (int*)(q + n);                      // nbuck
    int*   bstart = coltot + nbuck;                     // nbuck+1
    int*   Ht     = bstart + nbuck + 1;                 // nchunk*nbuck
    int*   Hs     = Ht + (size_t)nchunk * nbuck;        // nchunk*nbuck

    k_uw_hist<<<nchunk + 1, 256, 0, stream>>>(W1, b1, W2, u, col, Ht,
                                              nbuck, nchunk, e_cnt);
    k_gemv_colscan<<<nbCols + GEMV_BLOCKS, 256, 0, stream>>>(x, u, t, Ht, Hs, coltot,
                                                             n, nchunk, nbuck, nbCols);
    k_permute<<<nchunk, PNT, 0, stream>>>(row, col, w, Hs, coltot, bstart, ep,
                                          nbuck, e_cnt);
    k_adeg<<<nbuck, AGG_NT, 0, stream>>>(ep, bstart, t, dinv, p, n);
    k_as1<<<nbuck, AGG_NT, 0, stream>>>(ep, bstart, p, dinv, u, q, n);
    k_aout<<<nbuck, AGG_NT, 0, stream>>>(ep, bstart, q, dinv, b2, out, n);
}